// Round 4
// baseline (6360.997 us; speedup 1.0000x reference)
//
#include <hip/hip_runtime.h>
#include <hip/hip_bf16.h>

// Two-layer tanh RNN, B=32 T=512 I=512 H=1024, fp32 in/out, bf16 MFMA compute.
// Round-8: abandon hand-rolled sc0/sc1 scope engineering (rounds 5-7: two
// correctness failures traced to cached-stale-line hazards that manual scoped
// loads cannot fix without an invalidate). Use the HIP memory model instead:
//   producer: plain cached h stores -> fence(RELEASE, "agent") -> relaxed flag
//   consumer: relaxed flag poll -> fence(ACQUIRE, "agent") -> plain cached loads
// The compiler emits the architecturally-required buffer_wbl2 / buffer_inv
// sequences, correct for ANY workgroup placement. Perf win: h-data loads are
// now ordinary cached loads (L2 dedupes the 64KB h-slice across the 8-16 WGs
// per XCD) instead of round-4's L2-bypassing sc1 loads (4MB/step/layer of
// IC traffic, the suspected 9k-cycle/step hidden cost). Also: L1 keeps a
// shadow register of L0's monotone flag so the cross-layer poll (which also
// drained the out-stores, ~800cy) collapses to a register compare once L0
// runs ahead. Grid/workspace/MFMA-indexing/summation order are verbatim
// round-4 (2844us, passing) => bit-identical math.

#define B_ 32
#define T_ 512
#define I_ 512
#define H_ 1024

typedef __attribute__((ext_vector_type(8))) short short8;
typedef __attribute__((ext_vector_type(4))) float float4v;

// ---- workspace layout (bytes) — identical to round-4 ----
#define OFF_XBF   0ull            // x_bf : B*T*I bf16 = 16,777,216
#define OFF_H1    16777216ull     // h1buf: (T+1)*B*H bf16 = 33,619,968
#define OFF_HPING 50397184ull     // hping: 2*B*H bf16 = 131,072
#define OFF_FLAGS 50528256ull     // flags: 256 * 64 B

#define FENCE_REL() __builtin_amdgcn_fence(__ATOMIC_RELEASE, "agent")
#define FENCE_ACQ() __builtin_amdgcn_fence(__ATOMIC_ACQUIRE, "agent")

#define MFMA_B(acc, f, kb) \
  acc = __builtin_amdgcn_mfma_f32_16x16x32_bf16( \
      f, *reinterpret_cast<const short8*>(ldsW + (kb) * 512 + lofs), acc, 0, 0, 0)

// tanh(x) = 1 - 2/(exp2(2*log2e*x)+1); exact at saturation, ~1ulp rcp error
// (absorbed by bf16 storage).
__device__ __forceinline__ float fast_tanh(float x) {
  float z = fminf(2.885390081777927f * x, 60.0f);
  float e = __builtin_amdgcn_exp2f(z);
  return 1.0f - 2.0f * __builtin_amdgcn_rcpf(e + 1.0f);
}

// Lane l polls flag of (producer WG l, wave wid) until >= s. Relaxed only;
// the caller issues ONE acquire fence after the wait (covers all 64 lanes'
// producer pairings — fence/fence synchronizes-with via the observed flag).
__device__ __forceinline__ void wait_flags(const unsigned* fbase, int lane, int wid, unsigned s) {
  const unsigned* p = fbase + (((unsigned)lane << 1) + wid) * 16;
  while (__hip_atomic_load(p, __ATOMIC_RELAXED, __HIP_MEMORY_SCOPE_AGENT) < s)
    __builtin_amdgcn_s_sleep(1);
}

__global__ __launch_bounds__(128)
void rnn_fused(const float* __restrict__ Wih0, const float* __restrict__ Whh0,
               const float* __restrict__ bih0, const float* __restrict__ bhh0,
               const float* __restrict__ Wih1, const float* __restrict__ Whh1,
               const float* __restrict__ bih1, const float* __restrict__ bhh1,
               const __hip_bfloat16* __restrict__ x_bf,
               __hip_bfloat16* __restrict__ h1buf,
               __hip_bfloat16* __restrict__ hping,
               float* __restrict__ out,
               unsigned* __restrict__ flags)
{
  __shared__ unsigned short ldsW[16 * 2048];   // 64 KB (L0 uses 48 KB)
  const int tid  = threadIdx.x;
  const int wgid = blockIdx.x;
  const bool isL1 = (wgid >= 64);
  const int wg   = isL1 ? wgid - 64 : wgid;    // output cols wg*16..+16
  const int KIN  = isL1 ? H_ : I_;
  const int KTOT = KIN + H_;
  const float* Wih = isL1 ? Wih1 : Wih0;
  const float* Whh = isL1 ? Whh1 : Whh0;

  // Stage weight slice into LDS in MFMA B-fragment order (once).
  for (int idx = tid; idx < 16 * KTOT; idx += 128) {
    int c = idx / KTOT;
    int k = idx - c * KTOT;
    float w = (k < KIN) ? Wih[(size_t)(wg * 16 + c) * KIN + k]
                        : Whh[(size_t)(wg * 16 + c) * H_ + (k - KIN)];
    __hip_bfloat16 hb = __float2bfloat16(w);
    int pos = ((k >> 5) * 64 + ((k >> 3) & 3) * 16 + c) * 8 + (k & 7);
    ldsW[pos] = *reinterpret_cast<unsigned short*>(&hb);
  }

  const int lane  = tid & 63;
  const int wid   = tid >> 6;                    // m-tile: batch rows wid*16..+16
  const int col   = wg * 16 + (lane & 15);
  const float biasv = isL1 ? (bih1[col] + bhh1[col]) : (bih0[col] + bhh0[col]);
  const int arow  = wid * 16 + (lane & 15);      // A-frag row (batch index)
  const int ksub  = ((lane >> 4) & 3) * 8;       // A-frag k sub-offset
  const int lofs  = lane * 8;                    // B-frag LDS elem offset
  const int rbase = wid * 16 + (lane >> 4) * 4;  // C-frag row base
  const int r0    = (lane & 1) ? 2 : 0;          // rows this lane stores
  const int colp  = col & ~1;

  unsigned* fl0 = flags;
  unsigned* fl1 = flags + 128 * 16;
  unsigned* myflag = (isL1 ? fl1 : fl0) + (((unsigned)wg << 1) + wid) * 16;

  __syncthreads();   // weights staged (only __syncthreads in the kernel)

  if (!isL1) {
    // ================= layer 0 =================
    for (int s = 0; s < T_; ++s) {
      float4v accA = {biasv, biasv, biasv, biasv};
      float4v accB = {0.f, 0.f, 0.f, 0.f};
      // x-projection: read-only input, no ordering needed; issued before the
      // flag wait so its (possibly fence-invalidated) refetch hides there.
      const __hip_bfloat16* a0 = x_bf + (size_t)arow * (T_ * I_) + (size_t)s * I_ + ksub;
#pragma unroll
      for (int kb = 0; kb < 16; ++kb) {
        short8 av = *reinterpret_cast<const short8*>(a0 + kb * 32);
        MFMA_B(accA, av, kb);
      }
      if (s > 0) wait_flags(fl0, lane, wid, (unsigned)s);
      FENCE_ACQ();                 // buffer_inv: subsequent plain loads fresh
      const __hip_bfloat16* a1 = h1buf + (size_t)s * (B_ * H_) + (size_t)arow * H_ + ksub;
      short8 g[32];
#pragma unroll
      for (int kb = 0; kb < 32; ++kb)
        g[kb] = *reinterpret_cast<const short8*>(a1 + kb * 32);
#pragma unroll
      for (int kb = 0; kb < 32; ++kb) {
        if ((kb & 1) == 0) { MFMA_B(accA, g[kb], 16 + kb); }
        else               { MFMA_B(accB, g[kb], 16 + kb); }
      }

      __hip_bfloat16* hd = h1buf + (size_t)(s + 1) * (B_ * H_);
      float hv[4];
#pragma unroll
      for (int r = 0; r < 4; ++r) hv[r] = fast_tanh(accA[r] + accB[r]);
#pragma unroll
      for (int r = 0; r < 4; ++r) {
        float other = __shfl_xor(hv[r], 1, 64);
        float lo = (lane & 1) ? other : hv[r];
        float hi = (lane & 1) ? hv[r] : other;
        if (r == r0 || r == r0 + 1) {
          __hip_bfloat16 l16 = __float2bfloat16(lo), h16 = __float2bfloat16(hi);
          unsigned pk = (unsigned)*(unsigned short*)&l16 | ((unsigned)*(unsigned short*)&h16 << 16);
          *(unsigned*)(hd + (size_t)(rbase + r) * H_ + colp) = pk;   // plain cached store
        }
      }
      FENCE_REL();                 // wbl2: h visible at IC before flag
      if (lane == 0)
        __hip_atomic_store(myflag, (unsigned)(s + 1), __ATOMIC_RELAXED, __HIP_MEMORY_SCOPE_AGENT);
    }
  } else {
    // ================= layer 1 =================
    const unsigned* shp = fl0 + (((unsigned)lane << 1) + wid) * 16;
    unsigned sh = 0;   // shadow of my L0 producer's monotone flag: once L0
                       // runs ahead, the cross-layer wait is a reg compare.
    for (int t = 0; t < T_; ++t) {
      float4v accA = {biasv, biasv, biasv, biasv};
      float4v accB = {0.f, 0.f, 0.f, 0.f};
      unsigned need = (unsigned)(t + 1);
      while (sh < need) {
        sh = __hip_atomic_load(shp, __ATOMIC_RELAXED, __HIP_MEMORY_SCOPE_AGENT);
        if (sh < need) __builtin_amdgcn_s_sleep(1);
      }
      if (t > 0) wait_flags(fl1, lane, wid, (unsigned)t);
      FENCE_ACQ();                 // one acquire covers h1buf[t+1] AND hping
      const __hip_bfloat16* aA = h1buf + (size_t)(t + 1) * (B_ * H_) + (size_t)arow * H_ + ksub;
      short8 g[32];
#pragma unroll
      for (int kb = 0; kb < 32; ++kb)
        g[kb] = *reinterpret_cast<const short8*>(aA + kb * 32);
#pragma unroll
      for (int kb = 0; kb < 32; ++kb) {
        if ((kb & 1) == 0) { MFMA_B(accA, g[kb], kb); }
        else               { MFMA_B(accB, g[kb], kb); }
      }
      const __hip_bfloat16* aB = hping + (size_t)(t & 1) * (B_ * H_) + (size_t)arow * H_ + ksub;
      short8 h[32];
#pragma unroll
      for (int kb = 0; kb < 32; ++kb)
        h[kb] = *reinterpret_cast<const short8*>(aB + kb * 32);
#pragma unroll
      for (int kb = 0; kb < 32; ++kb) {
        if ((kb & 1) == 0) { MFMA_B(accA, h[kb], 32 + kb); }
        else               { MFMA_B(accB, h[kb], 32 + kb); }
      }

      __hip_bfloat16* hd = hping + (size_t)((t + 1) & 1) * (B_ * H_);
      float hv[4];
#pragma unroll
      for (int r = 0; r < 4; ++r) hv[r] = fast_tanh(accA[r] + accB[r]);
      float lov[4], hiv[4];
#pragma unroll
      for (int r = 0; r < 4; ++r) {
        float other = __shfl_xor(hv[r], 1, 64);
        lov[r] = (lane & 1) ? other : hv[r];
        hiv[r] = (lane & 1) ? hv[r] : other;
        if (r == r0 || r == r0 + 1) {
          __hip_bfloat16 l16 = __float2bfloat16(lov[r]), h16 = __float2bfloat16(hiv[r]);
          unsigned pk = (unsigned)*(unsigned short*)&l16 | ((unsigned)*(unsigned short*)&h16 << 16);
          *(unsigned*)(hd + (size_t)(rbase + r) * H_ + colp) = pk;   // plain cached store
        }
      }
      FENCE_REL();                 // hping visible at IC before flag
      if (lane == 0)
        __hip_atomic_store(myflag, (unsigned)(t + 1), __ATOMIC_RELAXED, __HIP_MEMORY_SCOPE_AGENT);
      // fp32 output stores AFTER the flag: off the critical path; drained by
      // the NEXT step's release fence (amortized) / end-of-kernel flush.
#pragma unroll
      for (int r = 0; r < 4; ++r) {
        if (r == r0 || r == r0 + 1) {
          float2 f2; f2.x = lov[r]; f2.y = hiv[r];
          *(float2*)(out + (size_t)(rbase + r) * (T_ * H_) + (size_t)t * H_ + colp) = f2;
        }
      }
    }
  }
}

// Re-init every call (ws poisoned 0xAA before each timed launch).
__global__ void prep_kernel(const float* __restrict__ x, unsigned long long* __restrict__ x64,
                            unsigned* __restrict__ h1z, unsigned* __restrict__ hpz,
                            unsigned* __restrict__ flags)
{
  int i = blockIdx.x * 256 + threadIdx.x;
  if (i < (B_ * T_ * I_) / 4) {
    const float4* x4 = (const float4*)x;
    float4 v = x4[i];
    __hip_bfloat16 b0 = __float2bfloat16(v.x), b1 = __float2bfloat16(v.y);
    __hip_bfloat16 b2 = __float2bfloat16(v.z), b3 = __float2bfloat16(v.w);
    unsigned long long r = (unsigned long long)*(unsigned short*)&b0
                         | ((unsigned long long)*(unsigned short*)&b1 << 16)
                         | ((unsigned long long)*(unsigned short*)&b2 << 32)
                         | ((unsigned long long)*(unsigned short*)&b3 << 48);
    x64[i] = r;
  }
  if (i < 16384) __hip_atomic_store(h1z + i, 0u, __ATOMIC_RELAXED, __HIP_MEMORY_SCOPE_AGENT);
  if (i < 32768) __hip_atomic_store(hpz + i, 0u, __ATOMIC_RELAXED, __HIP_MEMORY_SCOPE_AGENT);
  if (i < 4096)  __hip_atomic_store(flags + i, 0u, __ATOMIC_RELAXED, __HIP_MEMORY_SCOPE_AGENT);
}

extern "C" void kernel_launch(void* const* d_in, const int* in_sizes, int n_in,
                              void* d_out, int out_size, void* d_ws, size_t ws_size,
                              hipStream_t stream)
{
  const float* x    = (const float*)d_in[0];
  const float* Wih0 = (const float*)d_in[1];
  const float* Whh0 = (const float*)d_in[2];
  const float* bih0 = (const float*)d_in[3];
  const float* bhh0 = (const float*)d_in[4];
  const float* Wih1 = (const float*)d_in[5];
  const float* Whh1 = (const float*)d_in[6];
  const float* bih1 = (const float*)d_in[7];
  const float* bhh1 = (const float*)d_in[8];
  float* out = (float*)d_out;
  char* ws = (char*)d_ws;

  __hip_bfloat16* x_bf  = (__hip_bfloat16*)(ws + OFF_XBF);
  __hip_bfloat16* h1buf = (__hip_bfloat16*)(ws + OFF_H1);
  __hip_bfloat16* hping = (__hip_bfloat16*)(ws + OFF_HPING);
  unsigned* flags = (unsigned*)(ws + OFF_FLAGS);

  prep_kernel<<<(B_ * T_ * I_ / 4 + 255) / 256, 256, 0, stream>>>(
      x, (unsigned long long*)x_bf, (unsigned*)h1buf, (unsigned*)hping, flags);

  rnn_fused<<<128, 128, 0, stream>>>(Wih0, Whh0, bih0, bhh0,
                                     Wih1, Whh1, bih1, bhh1,
                                     x_bf, h1buf, hping, out, flags);
}

// Round 5
// 2969.945 us; speedup vs baseline: 2.1418x; 2.1418x over previous
//
#include <hip/hip_runtime.h>
#include <hip/hip_bf16.h>

// Two-layer tanh RNN, B=32 T=512 I=512 H=1024, fp32 in/out, bf16 MFMA compute.
// Round-9: R4 (2844us, proven) with ONE change - packed flag layout.
// R4 strided flags 64B apart: each poll iteration was a 64-lane gather over
// 64 DISTINCT IC lines, x128 waves, repeating with vmcnt(0) - ~8k concurrent
// poll streams colliding with h-store/ack/load traffic. Theory: this fabric
// contention inflates every round-trip in the serial handshake (13.3k cy/step
// measured vs ~5-6k budget). Packing flags at 4B stride (per layer, per wid:
// fbase + wid*64 + lane) makes one poll a 4-line stride-1 gather (16x less
// line traffic); producer publish is a plain sc1 dword store (fire-and-
// forget, write-combined at IC). Flag SEMANTICS identical to R4 (per-
// producer word, same ordering: h stores -> vmcnt(0) ack -> flag store).
// All data paths byte-identical to R4. R8's fences removed (cost 7us/step
// in cache maintenance); R6/R7 taught us cross-WG data must stay sc1/IC
// (shared-line staleness makes L2-cached transport unsound).

#define B_ 32
#define T_ 512
#define I_ 512
#define H_ 1024

typedef __attribute__((ext_vector_type(8))) short short8;
typedef __attribute__((ext_vector_type(4))) float float4v;

// ---- workspace layout (bytes) ----
#define OFF_XBF   0ull            // x_bf : B*T*I bf16 = 16,777,216
#define OFF_H1    16777216ull     // h1buf: (T+1)*B*H bf16 = 33,619,968
#define OFF_HPING 50397184ull     // hping: 2*B*H bf16 = 131,072
#define OFF_FLAGS 50528256ull     // flags: 16,384 B (fl0 @ u32 0, fl1 @ u32 128)

#define WAIT_VM0() asm volatile("s_waitcnt vmcnt(0)" ::: "memory")
#define CFENCE()   asm volatile("" ::: "memory")

// Issue one 16B L2-bypassing load (agent-coherent). No implicit wait.
#define LDF(f, base, O) \
  asm volatile("global_load_dwordx4 %0, %1, off offset:%2 sc1" \
               : "=v"(f) : "v"(base), "n"(O) : "memory")

// Issue 8 fragments from base + OB.. (+448). 64 B per fragment (32 bf16).
#define LD8(F, S, BASE, OB) \
  LDF(F[S+0], BASE, OB+0);   LDF(F[S+1], BASE, OB+64); \
  LDF(F[S+2], BASE, OB+128); LDF(F[S+3], BASE, OB+192); \
  LDF(F[S+4], BASE, OB+256); LDF(F[S+5], BASE, OB+320); \
  LDF(F[S+6], BASE, OB+384); LDF(F[S+7], BASE, OB+448)

// Wait until <=N vector-mem ops outstanding; ties the 8 fragments through the
// asm so the scheduler cannot hoist their consuming MFMAs above the wait.
// (vmcnt retires oldest-first, so extra older in-flight ops only over-wait.)
#define VMW8(N, F, S) \
  asm volatile("s_waitcnt vmcnt(" #N ")" \
               : "+v"(F[S+0]), "+v"(F[S+1]), "+v"(F[S+2]), "+v"(F[S+3]), \
                 "+v"(F[S+4]), "+v"(F[S+5]), "+v"(F[S+6]), "+v"(F[S+7]))

#define MFMA_B(acc, f, kb) \
  acc = __builtin_amdgcn_mfma_f32_16x16x32_bf16( \
      f, *reinterpret_cast<const short8*>(ldsW + (kb) * 512 + lofs), acc, 0, 0, 0)

// 8 MFMAs for fragments F[S..S+7] against k-blocks KB..KB+7, alternating two
// accumulator chains (halves the dependent-MFMA latency chain).
#define MF8(F, S, KB) \
  MFMA_B(accA, F[S+0], KB+0); MFMA_B(accB, F[S+1], KB+1); \
  MFMA_B(accA, F[S+2], KB+2); MFMA_B(accB, F[S+3], KB+3); \
  MFMA_B(accA, F[S+4], KB+4); MFMA_B(accB, F[S+5], KB+5); \
  MFMA_B(accA, F[S+6], KB+6); MFMA_B(accB, F[S+7], KB+7)

// tanh(x) = 1 - 2/(exp2(2*log2e*x)+1); exact at saturation, ~1ulp rcp error
// (absorbed by bf16 storage). Much shorter dependency chain than libm tanhf.
__device__ __forceinline__ float fast_tanh(float x) {
  float z = fminf(2.885390081777927f * x, 60.0f);
  float e = __builtin_amdgcn_exp2f(z);
  return 1.0f - 2.0f * __builtin_amdgcn_rcpf(e + 1.0f);
}

// Lane l polls flag of (producer WG l, wave wid) until >= s. Packed layout:
// 64 flags of one wid group span 256B (4 lines) - one stride-1 gather/iter.
__device__ __forceinline__ void wait_layer(unsigned* fbase, int lane, int wid, unsigned s) {
  unsigned* p = fbase + (unsigned)(wid * 64 + lane);
  while (__hip_atomic_load(p, __ATOMIC_RELAXED, __HIP_MEMORY_SCOPE_AGENT) < s)
    __builtin_amdgcn_s_sleep(1);
  CFENCE();
}

__global__ __launch_bounds__(128)
void rnn_fused(const float* __restrict__ Wih0, const float* __restrict__ Whh0,
               const float* __restrict__ bih0, const float* __restrict__ bhh0,
               const float* __restrict__ Wih1, const float* __restrict__ Whh1,
               const float* __restrict__ bih1, const float* __restrict__ bhh1,
               const __hip_bfloat16* __restrict__ x_bf,
               __hip_bfloat16* __restrict__ h1buf,
               __hip_bfloat16* __restrict__ hping,
               float* __restrict__ out,
               unsigned* __restrict__ flags)
{
  __shared__ unsigned short ldsW[16 * 2048];   // 64 KB (L0 uses 48 KB)
  const int tid  = threadIdx.x;
  const int wgid = blockIdx.x;
  const bool isL1 = (wgid >= 64);
  const int wg   = isL1 ? wgid - 64 : wgid;    // output cols wg*16..+16
  const int KIN  = isL1 ? H_ : I_;
  const int KTOT = KIN + H_;
  const float* Wih = isL1 ? Wih1 : Wih0;
  const float* Whh = isL1 ? Whh1 : Whh0;

  // Stage weight slice into LDS in MFMA B-fragment order (once).
  for (int idx = tid; idx < 16 * KTOT; idx += 128) {
    int c = idx / KTOT;
    int k = idx - c * KTOT;
    float w = (k < KIN) ? Wih[(size_t)(wg * 16 + c) * KIN + k]
                        : Whh[(size_t)(wg * 16 + c) * H_ + (k - KIN)];
    __hip_bfloat16 hb = __float2bfloat16(w);
    int pos = ((k >> 5) * 64 + ((k >> 3) & 3) * 16 + c) * 8 + (k & 7);
    ldsW[pos] = *reinterpret_cast<unsigned short*>(&hb);
  }

  const int lane  = tid & 63;
  const int wid   = tid >> 6;                    // m-tile: batch rows wid*16..+16
  const int col   = wg * 16 + (lane & 15);
  const float biasv = isL1 ? (bih1[col] + bhh1[col]) : (bih0[col] + bhh0[col]);
  const int arow  = wid * 16 + (lane & 15);      // A-frag row (batch index)
  const int ksub  = ((lane >> 4) & 3) * 8;       // A-frag k sub-offset
  const int lofs  = lane * 8;                    // B-frag LDS elem offset
  const int rbase = wid * 16 + (lane >> 4) * 4;  // C-frag row base
  const int r0    = (lane & 1) ? 2 : 0;          // rows this lane stores
  const int colp  = col & ~1;

  unsigned* fl0 = flags;            // [wid][wg] packed u32: 128 words
  unsigned* fl1 = flags + 128;
  unsigned* myflag = (isL1 ? fl1 : fl0) + (unsigned)(wid * 64 + wg);

  __syncthreads();   // weights staged (only __syncthreads in the kernel)

  if (!isL1) {
    // ================= layer 0 =================
    for (int s = 0; s < T_; ++s) {
      float4v accA = {biasv, biasv, biasv, biasv};
      float4v accB = {0.f, 0.f, 0.f, 0.f};
      // x-projection: cached loads, independent of the flag wait.
      const __hip_bfloat16* a0 = x_bf + (size_t)arow * (T_ * I_) + (size_t)s * I_ + ksub;
#pragma unroll
      for (int kb = 0; kb < 16; ++kb) {
        short8 av = *reinterpret_cast<const short8*>(a0 + kb * 32);
        MFMA_B(accA, av, kb);
      }
      if (s > 0) wait_layer(fl0, lane, wid, (unsigned)s);
      const __hip_bfloat16* a1 = h1buf + (size_t)s * (B_ * H_) + (size_t)arow * H_ + ksub;
      short8 g[32];
      LD8(g, 0, a1, 0);  LD8(g, 8, a1, 512);  LD8(g, 16, a1, 1024);  LD8(g, 24, a1, 1536);
      VMW8(24, g, 0);   MF8(g, 0, 16);
      VMW8(16, g, 8);   MF8(g, 8, 24);
      VMW8(8,  g, 16);  MF8(g, 16, 32);
      VMW8(0,  g, 24);  MF8(g, 24, 40);

      __hip_bfloat16* hd = h1buf + (size_t)(s + 1) * (B_ * H_);
      float hv[4];
#pragma unroll
      for (int r = 0; r < 4; ++r) hv[r] = fast_tanh(accA[r] + accB[r]);
#pragma unroll
      for (int r = 0; r < 4; ++r) {
        float other = __shfl_xor(hv[r], 1, 64);
        float lo = (lane & 1) ? other : hv[r];
        float hi = (lane & 1) ? hv[r] : other;
        if (r == r0 || r == r0 + 1) {
          __hip_bfloat16 l16 = __float2bfloat16(lo), h16 = __float2bfloat16(hi);
          unsigned pk = (unsigned)*(unsigned short*)&l16 | ((unsigned)*(unsigned short*)&h16 << 16);
          unsigned* dst = (unsigned*)(hd + (size_t)(rbase + r) * H_ + colp);
          __hip_atomic_store(dst, pk, __ATOMIC_RELAXED, __HIP_MEMORY_SCOPE_AGENT);
        }
      }
      WAIT_VM0();                                  // h acked at L3 (coherence point)
      if (lane == 0)
        __hip_atomic_store(myflag, (unsigned)(s + 1), __ATOMIC_RELAXED, __HIP_MEMORY_SCOPE_AGENT);
    }
  } else {
    // ================= layer 1 =================
    for (int t = 0; t < T_; ++t) {
      float4v accA = {biasv, biasv, biasv, biasv};
      float4v accB = {0.f, 0.f, 0.f, 0.f};
      wait_layer(fl0, lane, wid, (unsigned)(t + 1));   // L0 runs ahead: usually free
      if (t > 0) wait_layer(fl1, lane, wid, (unsigned)t);
      const __hip_bfloat16* aA = h1buf + (size_t)(t + 1) * (B_ * H_) + (size_t)arow * H_ + ksub;
      const __hip_bfloat16* aB = hping + (size_t)(t & 1) * (B_ * H_) + (size_t)arow * H_ + ksub;
      short8 g[32], h[32];
      LD8(g, 0, aA, 0);  LD8(g, 8, aA, 512);  LD8(g, 16, aA, 1024);  LD8(g, 24, aA, 1536);
      // Second half's loads issue under the first half's MFMAs (<=32 in flight).
      VMW8(24, g, 0);   MF8(g, 0, 0);    LD8(h, 0, aB, 0);
      VMW8(24, g, 8);   MF8(g, 8, 8);    LD8(h, 8, aB, 512);
      VMW8(24, g, 16);  MF8(g, 16, 16);  LD8(h, 16, aB, 1024);
      VMW8(24, g, 24);  MF8(g, 24, 24);  LD8(h, 24, aB, 1536);
      VMW8(24, h, 0);   MF8(h, 0, 32);
      VMW8(16, h, 8);   MF8(h, 8, 40);
      VMW8(8,  h, 16);  MF8(h, 16, 48);
      VMW8(0,  h, 24);  MF8(h, 24, 56);

      __hip_bfloat16* hd = hping + (size_t)((t + 1) & 1) * (B_ * H_);
      float hv[4];
#pragma unroll
      for (int r = 0; r < 4; ++r) hv[r] = fast_tanh(accA[r] + accB[r]);
      float lov[4], hiv[4];
#pragma unroll
      for (int r = 0; r < 4; ++r) {
        float other = __shfl_xor(hv[r], 1, 64);
        lov[r] = (lane & 1) ? other : hv[r];
        hiv[r] = (lane & 1) ? hv[r] : other;
        if (r == r0 || r == r0 + 1) {
          __hip_bfloat16 l16 = __float2bfloat16(lov[r]), h16 = __float2bfloat16(hiv[r]);
          unsigned pk = (unsigned)*(unsigned short*)&l16 | ((unsigned)*(unsigned short*)&h16 << 16);
          unsigned* dst = (unsigned*)(hd + (size_t)(rbase + r) * H_ + colp);
          __hip_atomic_store(dst, pk, __ATOMIC_RELAXED, __HIP_MEMORY_SCOPE_AGENT);
        }
      }
      WAIT_VM0();                                  // only the 2 h stores outstanding here
      if (lane == 0)
        __hip_atomic_store(myflag, (unsigned)(t + 1), __ATOMIC_RELAXED, __HIP_MEMORY_SCOPE_AGENT);
      // fp32 output stores AFTER the flag: off the critical path (drained by
      // next step's WAIT_VM0 / end-of-kernel flush).
#pragma unroll
      for (int r = 0; r < 4; ++r) {
        if (r == r0 || r == r0 + 1) {
          float2 f2; f2.x = lov[r]; f2.y = hiv[r];
          *(float2*)(out + (size_t)(rbase + r) * (T_ * H_) + (size_t)t * H_ + colp) = f2;
        }
      }
    }
  }
}

// Re-init every call (ws poisoned 0xAA before each timed launch).
__global__ void prep_kernel(const float* __restrict__ x, unsigned long long* __restrict__ x64,
                            unsigned* __restrict__ h1z, unsigned* __restrict__ hpz,
                            unsigned* __restrict__ flags)
{
  int i = blockIdx.x * 256 + threadIdx.x;
  if (i < (B_ * T_ * I_) / 4) {
    const float4* x4 = (const float4*)x;
    float4 v = x4[i];
    __hip_bfloat16 b0 = __float2bfloat16(v.x), b1 = __float2bfloat16(v.y);
    __hip_bfloat16 b2 = __float2bfloat16(v.z), b3 = __float2bfloat16(v.w);
    unsigned long long r = (unsigned long long)*(unsigned short*)&b0
                         | ((unsigned long long)*(unsigned short*)&b1 << 16)
                         | ((unsigned long long)*(unsigned short*)&b2 << 32)
                         | ((unsigned long long)*(unsigned short*)&b3 << 48);
    x64[i] = r;
  }
  if (i < 16384) __hip_atomic_store(h1z + i, 0u, __ATOMIC_RELAXED, __HIP_MEMORY_SCOPE_AGENT);
  if (i < 32768) __hip_atomic_store(hpz + i, 0u, __ATOMIC_RELAXED, __HIP_MEMORY_SCOPE_AGENT);
  if (i < 4096)  __hip_atomic_store(flags + i, 0u, __ATOMIC_RELAXED, __HIP_MEMORY_SCOPE_AGENT);
}

extern "C" void kernel_launch(void* const* d_in, const int* in_sizes, int n_in,
                              void* d_out, int out_size, void* d_ws, size_t ws_size,
                              hipStream_t stream)
{
  const float* x    = (const float*)d_in[0];
  const float* Wih0 = (const float*)d_in[1];
  const float* Whh0 = (const float*)d_in[2];
  const float* bih0 = (const float*)d_in[3];
  const float* bhh0 = (const float*)d_in[4];
  const float* Wih1 = (const float*)d_in[5];
  const float* Whh1 = (const float*)d_in[6];
  const float* bih1 = (const float*)d_in[7];
  const float* bhh1 = (const float*)d_in[8];
  float* out = (float*)d_out;
  char* ws = (char*)d_ws;

  __hip_bfloat16* x_bf  = (__hip_bfloat16*)(ws + OFF_XBF);
  __hip_bfloat16* h1buf = (__hip_bfloat16*)(ws + OFF_H1);
  __hip_bfloat16* hping = (__hip_bfloat16*)(ws + OFF_HPING);
  unsigned* flags = (unsigned*)(ws + OFF_FLAGS);

  prep_kernel<<<(B_ * T_ * I_ / 4 + 255) / 256, 256, 0, stream>>>(
      x, (unsigned long long*)x_bf, (unsigned*)h1buf, (unsigned*)hping, flags);

  rnn_fused<<<128, 128, 0, stream>>>(Wih0, Whh0, bih0, bhh0,
                                     Wih1, Whh1, bih1, bhh1,
                                     x_bf, h1buf, hping, out, flags);
}

// Round 7
// 2657.837 us; speedup vs baseline: 2.3933x; 1.1174x over previous
//
#include <hip/hip_runtime.h>
#include <hip/hip_bf16.h>

// Two-layer tanh RNN, B=32 T=512 I=512 H=1024, fp32 in/out, bf16 MFMA compute.
// Round-11: R4 base (2780us, proven). R10 failed because moving all g-MFMAs
// below the h-load issues made g[32]+h[32] fully co-live (~290 VGPR) ->
// scratch spills -> spill traffic increments vmcnt -> VMW8 counts broken ->
// garbage fragments. RULE: keep R4's consume-before-issue interleave; no
// compiler vmem ops between LD8 issues and their VMW8 waits.
// R11 = R4 + two surgical L1 changes that preserve that structure:
//  (1) fl0 (cross-layer) wait via per-lane shadow register (L0 free-runs
//      ahead; poll collapses to a register compare most steps).
//  (2) g-loads (h1buf) issued BEFORE the fl1 poll; the poll's embedded
//      vmcnt(0) drains them under the flag round trip. Downstream
//      VMW8(24,g,S) become no-ops/over-waits (g drained, only h pending) -
//      never under-waits; register peak at the poll is LOWER than R4's.
// L0 loop, flags layout, epilogues, prep, launch: byte-identical to R4.

#define B_ 32
#define T_ 512
#define I_ 512
#define H_ 1024

typedef __attribute__((ext_vector_type(8))) short short8;
typedef __attribute__((ext_vector_type(4))) float float4v;

// ---- workspace layout (bytes) ----
#define OFF_XBF   0ull            // x_bf : B*T*I bf16 = 16,777,216
#define OFF_H1    16777216ull     // h1buf: (T+1)*B*H bf16 = 33,619,968
#define OFF_HPING 50397184ull     // hping: 2*B*H bf16 = 131,072
#define OFF_FLAGS 50528256ull     // flags: 256 * 64 B

#define WAIT_VM0() asm volatile("s_waitcnt vmcnt(0)" ::: "memory")
#define CFENCE()   asm volatile("" ::: "memory")

// Issue one 16B L2-bypassing load (agent-coherent). No implicit wait.
#define LDF(f, base, O) \
  asm volatile("global_load_dwordx4 %0, %1, off offset:%2 sc1" \
               : "=v"(f) : "v"(base), "n"(O) : "memory")

// Issue 8 fragments from base + OB.. (+448). 64 B per fragment (32 bf16).
#define LD8(F, S, BASE, OB) \
  LDF(F[S+0], BASE, OB+0);   LDF(F[S+1], BASE, OB+64); \
  LDF(F[S+2], BASE, OB+128); LDF(F[S+3], BASE, OB+192); \
  LDF(F[S+4], BASE, OB+256); LDF(F[S+5], BASE, OB+320); \
  LDF(F[S+6], BASE, OB+384); LDF(F[S+7], BASE, OB+448)

// Wait until <=N vector-mem ops outstanding; ties the 8 fragments through the
// asm so the scheduler cannot hoist their consuming MFMAs above the wait.
// (vmcnt retires oldest-first, so extra older in-flight ops only over-wait.)
#define VMW8(N, F, S) \
  asm volatile("s_waitcnt vmcnt(" #N ")" \
               : "+v"(F[S+0]), "+v"(F[S+1]), "+v"(F[S+2]), "+v"(F[S+3]), \
                 "+v"(F[S+4]), "+v"(F[S+5]), "+v"(F[S+6]), "+v"(F[S+7]))

#define MFMA_B(acc, f, kb) \
  acc = __builtin_amdgcn_mfma_f32_16x16x32_bf16( \
      f, *reinterpret_cast<const short8*>(ldsW + (kb) * 512 + lofs), acc, 0, 0, 0)

// 8 MFMAs for fragments F[S..S+7] against k-blocks KB..KB+7, alternating two
// accumulator chains (halves the dependent-MFMA latency chain).
#define MF8(F, S, KB) \
  MFMA_B(accA, F[S+0], KB+0); MFMA_B(accB, F[S+1], KB+1); \
  MFMA_B(accA, F[S+2], KB+2); MFMA_B(accB, F[S+3], KB+3); \
  MFMA_B(accA, F[S+4], KB+4); MFMA_B(accB, F[S+5], KB+5); \
  MFMA_B(accA, F[S+6], KB+6); MFMA_B(accB, F[S+7], KB+7)

// tanh(x) = 1 - 2/(exp2(2*log2e*x)+1); exact at saturation, ~1ulp rcp error
// (absorbed by bf16 storage). Much shorter dependency chain than libm tanhf.
__device__ __forceinline__ float fast_tanh(float x) {
  float z = fminf(2.885390081777927f * x, 60.0f);
  float e = __builtin_amdgcn_exp2f(z);
  return 1.0f - 2.0f * __builtin_amdgcn_rcpf(e + 1.0f);
}

// Lane l polls flag of (producer WG l, wave wid) until >= s.
__device__ __forceinline__ void wait_layer(unsigned* fbase, int lane, int wid, unsigned s) {
  unsigned* p = fbase + (((unsigned)lane << 1) + wid) * 16;
  while (__hip_atomic_load(p, __ATOMIC_RELAXED, __HIP_MEMORY_SCOPE_AGENT) < s)
    __builtin_amdgcn_s_sleep(1);
  CFENCE();
}

__global__ __launch_bounds__(128)
void rnn_fused(const float* __restrict__ Wih0, const float* __restrict__ Whh0,
               const float* __restrict__ bih0, const float* __restrict__ bhh0,
               const float* __restrict__ Wih1, const float* __restrict__ Whh1,
               const float* __restrict__ bih1, const float* __restrict__ bhh1,
               const __hip_bfloat16* __restrict__ x_bf,
               __hip_bfloat16* __restrict__ h1buf,
               __hip_bfloat16* __restrict__ hping,
               float* __restrict__ out,
               unsigned* __restrict__ flags)
{
  __shared__ unsigned short ldsW[16 * 2048];   // 64 KB (L0 uses 48 KB)
  const int tid  = threadIdx.x;
  const int wgid = blockIdx.x;
  const bool isL1 = (wgid >= 64);
  const int wg   = isL1 ? wgid - 64 : wgid;    // output cols wg*16..+16
  const int KIN  = isL1 ? H_ : I_;
  const int KTOT = KIN + H_;
  const float* Wih = isL1 ? Wih1 : Wih0;
  const float* Whh = isL1 ? Whh1 : Whh0;

  // Stage weight slice into LDS in MFMA B-fragment order (once).
  for (int idx = tid; idx < 16 * KTOT; idx += 128) {
    int c = idx / KTOT;
    int k = idx - c * KTOT;
    float w = (k < KIN) ? Wih[(size_t)(wg * 16 + c) * KIN + k]
                        : Whh[(size_t)(wg * 16 + c) * H_ + (k - KIN)];
    __hip_bfloat16 hb = __float2bfloat16(w);
    int pos = ((k >> 5) * 64 + ((k >> 3) & 3) * 16 + c) * 8 + (k & 7);
    ldsW[pos] = *reinterpret_cast<unsigned short*>(&hb);
  }

  const int lane  = tid & 63;
  const int wid   = tid >> 6;                    // m-tile: batch rows wid*16..+16
  const int col   = wg * 16 + (lane & 15);
  const float biasv = isL1 ? (bih1[col] + bhh1[col]) : (bih0[col] + bhh0[col]);
  const int arow  = wid * 16 + (lane & 15);      // A-frag row (batch index)
  const int ksub  = ((lane >> 4) & 3) * 8;       // A-frag k sub-offset
  const int lofs  = lane * 8;                    // B-frag LDS elem offset
  const int rbase = wid * 16 + (lane >> 4) * 4;  // C-frag row base
  const int r0    = (lane & 1) ? 2 : 0;          // rows this lane stores
  const int colp  = col & ~1;

  unsigned* fl0 = flags;
  unsigned* fl1 = flags + 128 * 16;
  unsigned* myflag = (isL1 ? fl1 : fl0) + (((unsigned)wg << 1) + wid) * 16;

  __syncthreads();   // weights staged (only __syncthreads in the kernel)

  if (!isL1) {
    // ================= layer 0 (byte-identical to R4) =================
    for (int s = 0; s < T_; ++s) {
      float4v accA = {biasv, biasv, biasv, biasv};
      float4v accB = {0.f, 0.f, 0.f, 0.f};
      // x-projection: cached loads, independent of the flag wait.
      const __hip_bfloat16* a0 = x_bf + (size_t)arow * (T_ * I_) + (size_t)s * I_ + ksub;
#pragma unroll
      for (int kb = 0; kb < 16; ++kb) {
        short8 av = *reinterpret_cast<const short8*>(a0 + kb * 32);
        MFMA_B(accA, av, kb);
      }
      if (s > 0) wait_layer(fl0, lane, wid, (unsigned)s);
      const __hip_bfloat16* a1 = h1buf + (size_t)s * (B_ * H_) + (size_t)arow * H_ + ksub;
      short8 g[32];
      LD8(g, 0, a1, 0);  LD8(g, 8, a1, 512);  LD8(g, 16, a1, 1024);  LD8(g, 24, a1, 1536);
      VMW8(24, g, 0);   MF8(g, 0, 16);
      VMW8(16, g, 8);   MF8(g, 8, 24);
      VMW8(8,  g, 16);  MF8(g, 16, 32);
      VMW8(0,  g, 24);  MF8(g, 24, 40);

      __hip_bfloat16* hd = h1buf + (size_t)(s + 1) * (B_ * H_);
      float hv[4];
#pragma unroll
      for (int r = 0; r < 4; ++r) hv[r] = fast_tanh(accA[r] + accB[r]);
#pragma unroll
      for (int r = 0; r < 4; ++r) {
        float other = __shfl_xor(hv[r], 1, 64);
        float lo = (lane & 1) ? other : hv[r];
        float hi = (lane & 1) ? hv[r] : other;
        if (r == r0 || r == r0 + 1) {
          __hip_bfloat16 l16 = __float2bfloat16(lo), h16 = __float2bfloat16(hi);
          unsigned pk = (unsigned)*(unsigned short*)&l16 | ((unsigned)*(unsigned short*)&h16 << 16);
          unsigned* dst = (unsigned*)(hd + (size_t)(rbase + r) * H_ + colp);
          __hip_atomic_store(dst, pk, __ATOMIC_RELAXED, __HIP_MEMORY_SCOPE_AGENT);
        }
      }
      WAIT_VM0();                                  // h acked at L3 (coherence point)
      if (lane == 0)
        __hip_atomic_store(myflag, (unsigned)(s + 1), __ATOMIC_RELAXED, __HIP_MEMORY_SCOPE_AGENT);
    }
  } else {
    // ================= layer 1 (R4 + shadow-fl0 + g-preissue) =================
    const unsigned* shp = fl0 + (((unsigned)lane << 1) + wid) * 16;
    unsigned shA = 0;   // per-lane shadow of my L0 producer's monotone flag
    for (int t = 0; t < T_; ++t) {
      float4v accA = {biasv, biasv, biasv, biasv};
      float4v accB = {0.f, 0.f, 0.f, 0.f};
      unsigned need = (unsigned)(t + 1);
      // (1) cross-layer wait: register compare once L0 leads (most steps).
      while (shA < need) {
        shA = __hip_atomic_load(shp, __ATOMIC_RELAXED, __HIP_MEMORY_SCOPE_AGENT);
        if (shA < need) __builtin_amdgcn_s_sleep(1);
      }
      CFENCE();
      // (2) g-loads issued BEFORE the fl1 poll: the poll's embedded vmcnt(0)
      // drains them under the flag round trip.
      const __hip_bfloat16* aA = h1buf + (size_t)(t + 1) * (B_ * H_) + (size_t)arow * H_ + ksub;
      short8 g[32], h[32];
      LD8(g, 0, aA, 0);  LD8(g, 8, aA, 512);  LD8(g, 16, aA, 1024);  LD8(g, 24, aA, 1536);
      if (t > 0) wait_layer(fl1, lane, wid, (unsigned)t);
      else       WAIT_VM0();
      __builtin_amdgcn_sched_barrier(0);   // keep MFMAs below the poll/drain
      const __hip_bfloat16* aB = hping + (size_t)(t & 1) * (B_ * H_) + (size_t)arow * H_ + ksub;
      // R4's exact interleave. g is already drained, so VMW8(24,g,S) are
      // no-ops/over-waits - never under-waits; h counts are exact as in R4.
      VMW8(24, g, 0);   MF8(g, 0, 0);    LD8(h, 0, aB, 0);
      VMW8(24, g, 8);   MF8(g, 8, 8);    LD8(h, 8, aB, 512);
      VMW8(24, g, 16);  MF8(g, 16, 16);  LD8(h, 16, aB, 1024);
      VMW8(24, g, 24);  MF8(g, 24, 24);  LD8(h, 24, aB, 1536);
      VMW8(24, h, 0);   MF8(h, 0, 32);
      VMW8(16, h, 8);   MF8(h, 8, 40);
      VMW8(8,  h, 16);  MF8(h, 16, 48);
      VMW8(0,  h, 24);  MF8(h, 24, 56);

      __hip_bfloat16* hd = hping + (size_t)((t + 1) & 1) * (B_ * H_);
      float hv[4];
#pragma unroll
      for (int r = 0; r < 4; ++r) hv[r] = fast_tanh(accA[r] + accB[r]);
      float lov[4], hiv[4];
#pragma unroll
      for (int r = 0; r < 4; ++r) {
        float other = __shfl_xor(hv[r], 1, 64);
        lov[r] = (lane & 1) ? other : hv[r];
        hiv[r] = (lane & 1) ? hv[r] : other;
        if (r == r0 || r == r0 + 1) {
          __hip_bfloat16 l16 = __float2bfloat16(lov[r]), h16 = __float2bfloat16(hiv[r]);
          unsigned pk = (unsigned)*(unsigned short*)&l16 | ((unsigned)*(unsigned short*)&h16 << 16);
          unsigned* dst = (unsigned*)(hd + (size_t)(rbase + r) * H_ + colp);
          __hip_atomic_store(dst, pk, __ATOMIC_RELAXED, __HIP_MEMORY_SCOPE_AGENT);
        }
      }
      WAIT_VM0();                                  // only the 2 h stores outstanding here
      if (lane == 0)
        __hip_atomic_store(myflag, (unsigned)(t + 1), __ATOMIC_RELAXED, __HIP_MEMORY_SCOPE_AGENT);
      // fp32 output stores AFTER the flag: off the critical path (drained by
      // next step's WAIT_VM0 / end-of-kernel flush).
#pragma unroll
      for (int r = 0; r < 4; ++r) {
        if (r == r0 || r == r0 + 1) {
          float2 f2; f2.x = lov[r]; f2.y = hiv[r];
          *(float2*)(out + (size_t)(rbase + r) * (T_ * H_) + (size_t)t * H_ + colp) = f2;
        }
      }
    }
  }
}

// Re-init every call (ws poisoned 0xAA before each timed launch).
__global__ void prep_kernel(const float* __restrict__ x, unsigned long long* __restrict__ x64,
                            unsigned* __restrict__ h1z, unsigned* __restrict__ hpz,
                            unsigned* __restrict__ flags)
{
  int i = blockIdx.x * 256 + threadIdx.x;
  if (i < (B_ * T_ * I_) / 4) {
    const float4* x4 = (const float4*)x;
    float4 v = x4[i];
    __hip_bfloat16 b0 = __float2bfloat16(v.x), b1 = __float2bfloat16(v.y);
    __hip_bfloat16 b2 = __float2bfloat16(v.z), b3 = __float2bfloat16(v.w);
    unsigned long long r = (unsigned long long)*(unsigned short*)&b0
                         | ((unsigned long long)*(unsigned short*)&b1 << 16)
                         | ((unsigned long long)*(unsigned short*)&b2 << 32)
                         | ((unsigned long long)*(unsigned short*)&b3 << 48);
    x64[i] = r;
  }
  if (i < 16384) __hip_atomic_store(h1z + i, 0u, __ATOMIC_RELAXED, __HIP_MEMORY_SCOPE_AGENT);
  if (i < 32768) __hip_atomic_store(hpz + i, 0u, __ATOMIC_RELAXED, __HIP_MEMORY_SCOPE_AGENT);
  if (i < 4096)  __hip_atomic_store(flags + i, 0u, __ATOMIC_RELAXED, __HIP_MEMORY_SCOPE_AGENT);
}

extern "C" void kernel_launch(void* const* d_in, const int* in_sizes, int n_in,
                              void* d_out, int out_size, void* d_ws, size_t ws_size,
                              hipStream_t stream)
{
  const float* x    = (const float*)d_in[0];
  const float* Wih0 = (const float*)d_in[1];
  const float* Whh0 = (const float*)d_in[2];
  const float* bih0 = (const float*)d_in[3];
  const float* bhh0 = (const float*)d_in[4];
  const float* Wih1 = (const float*)d_in[5];
  const float* Whh1 = (const float*)d_in[6];
  const float* bih1 = (const float*)d_in[7];
  const float* bhh1 = (const float*)d_in[8];
  float* out = (float*)d_out;
  char* ws = (char*)d_ws;

  __hip_bfloat16* x_bf  = (__hip_bfloat16*)(ws + OFF_XBF);
  __hip_bfloat16* h1buf = (__hip_bfloat16*)(ws + OFF_H1);
  __hip_bfloat16* hping = (__hip_bfloat16*)(ws + OFF_HPING);
  unsigned* flags = (unsigned*)(ws + OFF_FLAGS);

  prep_kernel<<<(B_ * T_ * I_ / 4 + 255) / 256, 256, 0, stream>>>(
      x, (unsigned long long*)x_bf, (unsigned*)h1buf, (unsigned*)hping, flags);

  rnn_fused<<<128, 128, 0, stream>>>(Wih0, Whh0, bih0, bhh0,
                                     Wih1, Whh1, bih1, bhh1,
                                     x_bf, h1buf, hping, out, flags);
}